// Round 10
// baseline (1212.957 us; speedup 1.0000x reference)
//
#include <hip/hip_runtime.h>
#include <math.h>

// ---------------------------------------------------------------------------
// GaitGraph: standardize -> GCN(2->64)+ReLU -> GCN(64->64)+ReLU -> mean-pool
//            -> linear 64->3.   N=50000, E=800000, G=2048, H=64.
// R1: dst-CSR + pull-gather (585 -> 327us).
// R4: rank-2 layer-1 collapse + reg-tile GEMM + sorted pooling (-> 237us).
// R6/R7: layer-2 GEMM/agg swap + gemmB spill fix (-> 187us).
// R8/R9: u16 CSR + fused gathgemm w/ contiguous-range LDS-broadcast (-> 181us).
// R10: k_scatter16 wrote 41MB for 1.6MB payload (26x line-granular amp from
//      50000 cold cursors x 8 XCDs). Replaced by 2-level MSD counting sort:
//      256 coarse buckets (hot cursors + XCD-affinity filtered scatter), then
//      per-bucket LDS counting sort emitting csr16 + counts + offsets
//      (deletes k_degpack's 800K random atomics and the scan1/2/3 chain).
// ---------------------------------------------------------------------------

#define H 64
#define NB 256

__device__ __forceinline__ float nan0(float v) {
    return isfinite(v) ? v : 0.0f;
}

// Load index i from a buffer that is either int32 or int64 (flag is64).
__device__ __forceinline__ int ld_idx(const void* p, long long i, int is64) {
    if (is64) return (int)((const long long*)p)[i];
    return ((const int*)p)[i];
}

// Column sums + sumsq of the 2 input features (with nan_to_num).
// Block 0 additionally detects int64 vs int32 for edge_index and batch
// (odd int32 words all zero => int64 high words).
__global__ void k_stats(const float* __restrict__ x, int N,
                        float* __restrict__ stats,
                        const int* ei, int nEi, const int* batch, int nB,
                        int* flags) {
    if (blockIdx.x == 0) {
        __shared__ int nz_e, nz_b;
        if (threadIdx.x == 0) { nz_e = 0; nz_b = 0; }
        __syncthreads();
        int i = threadIdx.x;  // 0..255
        long long pe = 1 + 2 * ((long long)i * ((nEi - 2) / 2) / 256);
        if (pe < nEi && ei[pe] != 0) nz_e = 1;
        long long pb = 1 + 2 * ((long long)i * ((nB - 2) / 2) / 256);
        if (pb < nB && batch[pb] != 0) nz_b = 1;
        __syncthreads();
        if (threadIdx.x == 0) {
            flags[0] = (nz_e == 0);
            flags[1] = (nz_b == 0);
        }
    }
    float s0 = 0, s1 = 0, q0 = 0, q1 = 0;
    int tid = blockIdx.x * blockDim.x + threadIdx.x;
    int stride = gridDim.x * blockDim.x;
    for (int n = tid; n < N; n += stride) {
        float2 v = reinterpret_cast<const float2*>(x)[n];
        float a = nan0(v.x), b = nan0(v.y);
        s0 += a; s1 += b; q0 += a * a; q1 += b * b;
    }
    for (int m = 32; m >= 1; m >>= 1) {
        s0 += __shfl_down(s0, m);
        s1 += __shfl_down(s1, m);
        q0 += __shfl_down(q0, m);
        q1 += __shfl_down(q1, m);
    }
    __shared__ float red[4][4];
    int w = threadIdx.x >> 6, lane = threadIdx.x & 63;
    if (lane == 0) { red[w][0] = s0; red[w][1] = s1; red[w][2] = q0; red[w][3] = q1; }
    __syncthreads();
    if (threadIdx.x == 0) {
        int nw = blockDim.x >> 6;
        float t0 = 0, t1 = 0, t2 = 0, t3 = 0;
        for (int i = 0; i < nw; i++) {
            t0 += red[i][0]; t1 += red[i][1]; t2 += red[i][2]; t3 += red[i][3];
        }
        atomicAdd(&stats[0], t0);
        atomicAdd(&stats[1], t1);
        atomicAdd(&stats[2], t2);
        atomicAdd(&stats[3], t3);
    }
}

// Pack edges (dst<<16|src) coalesced + LDS-aggregated coarse-bucket histogram.
__global__ void k_count(const void* ei, int E, unsigned* __restrict__ packed,
                        int* __restrict__ bcnt, const int* __restrict__ flags) {
    __shared__ int hist[NB];
    for (int i = threadIdx.x; i < NB; i += 256) hist[i] = 0;
    __syncthreads();
    int is64 = flags[0];
    int stride = gridDim.x * 256;
    for (int e = blockIdx.x * 256 + threadIdx.x; e < E; e += stride) {
        unsigned s = (unsigned)ld_idx(ei, e, is64);
        unsigned d = (unsigned)ld_idx(ei, (long long)E + e, is64);
        packed[e] = (d << 16) | s;
        atomicAdd(&hist[d >> 8], 1);
    }
    __syncthreads();
    for (int i = threadIdx.x; i < NB; i += 256)
        if (hist[i]) atomicAdd(&bcnt[i], hist[i]);
}

// Scan 256 bucket counts -> bases + cursors; set sentinels.
__global__ void k_bscan(const int* __restrict__ bcnt, int* __restrict__ bbase,
                        int* __restrict__ bcur, int* __restrict__ offsets,
                        int N, int E) {
    __shared__ int tmp[NB];
    int v = bcnt[threadIdx.x];
    tmp[threadIdx.x] = v;
    __syncthreads();
    for (int off = 1; off < NB; off <<= 1) {
        int t = (threadIdx.x >= off) ? tmp[threadIdx.x - off] : 0;
        __syncthreads();
        tmp[threadIdx.x] += t;
        __syncthreads();
    }
    int ex = tmp[threadIdx.x] - v;
    bbase[threadIdx.x] = ex;
    bcur[threadIdx.x] = ex;
    if (threadIdx.x == 0) { bbase[NB] = E; offsets[N] = E; }
}

// Coarse scatter into bucket-grouped array. XCD-affinity: block class
// (blockIdx&7) only writes buckets with (b&7)==class, so each cache line is
// dirtied by ~one XCD (blockIdx round-robins XCDs). Edges re-read 8x (L3).
__global__ void k_bscatter(const unsigned* __restrict__ packed,
                           int* __restrict__ bcur,
                           unsigned* __restrict__ binned, int E) {
    unsigned cls = blockIdx.x & 7;
    int q = blockIdx.x >> 3;
    int nq = gridDim.x >> 3;
    long long beg = (long long)q * E / nq;
    long long end = (long long)(q + 1) * E / nq;
    for (long long e = beg + threadIdx.x; e < end; e += 256) {
        unsigned p = packed[e];
        if (((p >> 24) & 7u) == cls) {
            int pos = atomicAdd(&bcur[p >> 24], 1);
            binned[pos] = p;
        }
    }
}

// Per-bucket counting sort: one block per bucket (256 local dst slots).
// Emits final csr16 segment + per-node degree counts + CSR offsets.
__global__ __launch_bounds__(256) void k_bsort(
    const unsigned* __restrict__ binned, const int* __restrict__ bbase,
    unsigned short* __restrict__ csr16, int* __restrict__ counts,
    int* __restrict__ offsets, int N) {
    __shared__ int hist[NB], tmp[NB], cur[NB];
    int b = blockIdx.x;
    int beg = bbase[b], end = bbase[b + 1];
    hist[threadIdx.x] = 0;
    __syncthreads();
    for (int i = beg + threadIdx.x; i < end; i += 256)
        atomicAdd(&hist[(binned[i] >> 16) & 0xff], 1);
    __syncthreads();
    int v = hist[threadIdx.x];
    tmp[threadIdx.x] = v;
    __syncthreads();
    for (int off = 1; off < NB; off <<= 1) {
        int t = (threadIdx.x >= off) ? tmp[threadIdx.x - off] : 0;
        __syncthreads();
        tmp[threadIdx.x] += t;
        __syncthreads();
    }
    int ex = tmp[threadIdx.x] - v;
    cur[threadIdx.x] = ex;
    int n = b * NB + threadIdx.x;
    if (n < N) { counts[n] = v; offsets[n] = beg + ex; }
    __syncthreads();
    for (int i = beg + threadIdx.x; i < end; i += 256) {
        unsigned p = binned[i];
        int t = atomicAdd(&cur[(p >> 16) & 0xff], 1);
        csr16[beg + t] = (unsigned short)(p & 0xffffu);
    }
}

// T[n] = dinv[n] * standardized x[n]  (stats-derived constants inline).
__global__ void k_prepT(const float* __restrict__ x,
                        const float* __restrict__ stats,
                        const int* __restrict__ counts,
                        float2* __restrict__ T, int N) {
    int n = blockIdx.x * blockDim.x + threadIdx.x;
    if (n >= N) return;
    float sum0 = stats[0], sum1 = stats[1], q0 = stats[2], q1 = stats[3];
    float mu0 = sum0 / N, mu1 = sum1 / N;
    float v0 = fmaxf((q0 - sum0 * sum0 / N) / (N - 1), 0.0f);
    float v1 = fmaxf((q1 - sum1 * sum1 / N) / (N - 1), 0.0f);
    float r0 = 1.0f / (sqrtf(v0) + 1e-6f);
    float r1 = 1.0f / (sqrtf(v1) + 1e-6f);
    float di = rsqrtf((float)(counts[n] + 1));
    float2 xv = reinterpret_cast<const float2*>(x)[n];
    T[n] = make_float2(di * (nan0(xv.x) - mu0) * r0,
                       di * (nan0(xv.y) - mu1) * r1);
}

// Layer-1 aggregation on pre-scaled T: S[d] = di*(sum_e T[s] + T[d]).
// Emits Q[n] = (S0*di, S1*di, di, 0) for the layer-2 gather.
__global__ void k_aggQ(const unsigned short* __restrict__ csr16,
                       const int* __restrict__ offsets,
                       const float2* __restrict__ T,
                       const int* __restrict__ counts,
                       float4* __restrict__ Q, int N) {
    int n = blockIdx.x * blockDim.x + threadIdx.x;
    if (n >= N) return;
    float di = rsqrtf((float)(counts[n] + 1));
    float2 t = T[n];
    float s0 = t.x, s1 = t.y;  // self term (already dinv-scaled)
    int beg = offsets[n], end = offsets[n + 1];
    for (int k = beg; k < end; k++) {
        float2 ts = T[csr16[k]];
        s0 += ts.x; s1 += ts.y;
    }
    Q[n] = make_float4(s0 * di * di, s1 * di * di, di, 0.0f);
}

// Fused layer-2 aggregation + GEMM + bias + relu.
// Block = 64 dst rows, 256 threads; wave w owns rows [w*16, w*16+16), whose
// edges are one CONTIGUOUS u16-CSR range. Phase 1: flat 64-edge chunks:
// full-width gather of Q entries into a per-wave LDS chunk, then per edge one
// broadcast ds_read_b128 + 5 VALU (relu pos-homogeneity folds the edge weight
// into Q). Phase 2: register-tile GEMM @W2+b2+relu.
__global__ __launch_bounds__(256, 4) void k_gathgemm(
    const unsigned short* __restrict__ csr16, const int* __restrict__ offsets,
    const float4* __restrict__ Q, const float* __restrict__ W1,
    const float* __restrict__ b1, const float* __restrict__ W2,
    const float* __restrict__ b2, float* __restrict__ Bout, int N) {
    __shared__ float At[64][68];      // At[j][r] = aggY[r][j], pitch 68
    __shared__ float Ws[64][64];
    __shared__ float bs[64];
    __shared__ float4 chunkW[4][64];  // per-wave gathered Q entries
    int tid = threadIdx.x;
    for (int i = tid; i < 64 * 64; i += 256) Ws[i >> 6][i & 63] = W2[i];
    if (tid < 64) bs[tid] = b2[tid];
    int rbase = blockIdx.x * 64;
    int wid = tid >> 6, j = tid & 63;
    float w10 = W1[j], w11 = W1[H + j], bb = b1[j];

    int r0 = min(rbase + wid * 16, N);
    int r1 = min(r0 + 16, N);
    if (r0 < r1) {
        int eEnd = offsets[r1];
        int row = r0;
        int rowEnd = offsets[row + 1];
        float4 qd = Q[row];
        float di = qd.z;
        float acc = fmaxf(qd.x * w10 + qd.y * w11 + qd.z * bb, 0.0f);  // self
        for (int base = offsets[r0]; base < eEnd; base += 64) {
            if (base + j < eEnd) chunkW[wid][j] = Q[csr16[base + j]];
            int cnt = min(64, eEnd - base);
            for (int k = 0; k < cnt; k++) {
                int ecur = base + k;            // wave-uniform
                while (ecur >= rowEnd) {        // row(s) complete
                    At[j][row - rbase] = di * acc;
                    row++;
                    rowEnd = offsets[row + 1];
                    qd = Q[row];
                    di = qd.z;
                    acc = fmaxf(qd.x * w10 + qd.y * w11 + qd.z * bb, 0.0f);
                }
                float4 q = chunkW[wid][k];      // LDS broadcast read
                acc += fmaxf(q.x * w10 + q.y * w11 + q.z * bb, 0.0f);
            }
        }
        while (row < r1) {
            At[j][row - rbase] = di * acc;
            row++;
            if (row < r1) {
                rowEnd = offsets[row + 1];
                qd = Q[row];
                di = qd.z;
                acc = fmaxf(qd.x * w10 + qd.y * w11 + qd.z * bb, 0.0f);
            }
        }
    }
    __syncthreads();
    int rg = (tid & 15) * 4;  // row group
    int cg = (tid >> 4) * 4;  // col group
    float acc2[4][4] = {{0}};
#pragma unroll 8
    for (int k = 0; k < 64; k++) {
        float4 a = *reinterpret_cast<const float4*>(&At[k][rg]);
        float4 b = *reinterpret_cast<const float4*>(&Ws[k][cg]);
        acc2[0][0] += a.x * b.x; acc2[0][1] += a.x * b.y;
        acc2[0][2] += a.x * b.z; acc2[0][3] += a.x * b.w;
        acc2[1][0] += a.y * b.x; acc2[1][1] += a.y * b.y;
        acc2[1][2] += a.y * b.z; acc2[1][3] += a.y * b.w;
        acc2[2][0] += a.z * b.x; acc2[2][1] += a.z * b.y;
        acc2[2][2] += a.z * b.z; acc2[2][3] += a.z * b.w;
        acc2[3][0] += a.w * b.x; acc2[3][1] += a.w * b.y;
        acc2[3][2] += a.w * b.z; acc2[3][3] += a.w * b.w;
    }
#pragma unroll
    for (int i2 = 0; i2 < 4; i2++) {
        int r = rbase + rg + i2;
        if (r < N) {
            *reinterpret_cast<float4*>(&Bout[(size_t)r * H + cg]) = make_float4(
                fmaxf(acc2[i2][0] + bs[cg + 0], 0.0f),
                fmaxf(acc2[i2][1] + bs[cg + 1], 0.0f),
                fmaxf(acc2[i2][2] + bs[cg + 2], 0.0f),
                fmaxf(acc2[i2][3] + bs[cg + 3], 0.0f));
        }
    }
}

// Mean-pool per graph (sorted batch; inline binary search) + 64x3 classify.
__global__ __launch_bounds__(256) void k_poolcls(
    const float* __restrict__ B, const void* batch,
    const float* __restrict__ Wc, const float* __restrict__ bc,
    float* __restrict__ out, int N, int G, const int* __restrict__ flags) {
    int t = blockIdx.x * blockDim.x + threadIdx.x;
    int g = t >> 6, j = t & 63;
    if (g >= G) return;
    int is64 = flags[1];
    int beg, end;
    {
        int lo = 0, hi = N;
        while (lo < hi) {
            int mid = (lo + hi) >> 1;
            if (ld_idx(batch, mid, is64) < g) lo = mid + 1; else hi = mid;
        }
        beg = lo;
    }
    {
        int lo = beg, hi = N;
        while (lo < hi) {
            int mid = (lo + hi) >> 1;
            if (ld_idx(batch, mid, is64) < g + 1) lo = mid + 1; else hi = mid;
        }
        end = lo;
    }
    float acc = 0.0f;
    for (int n = beg; n < end; n++) acc += B[(size_t)n * H + j];
    float p = acc / (float)max(end - beg, 1);
#pragma unroll
    for (int c = 0; c < 3; c++) {
        float v = p * Wc[j * 3 + c];
        for (int m = 32; m >= 1; m >>= 1) v += __shfl_xor(v, m);
        if (j == 0) out[g * 3 + c] = v + bc[c];
    }
}

extern "C" void kernel_launch(void* const* d_in, const int* in_sizes, int n_in,
                              void* d_out, int out_size, void* d_ws,
                              size_t ws_size, hipStream_t stream) {
    const float* x  = (const float*)d_in[0];
    const float* W1 = (const float*)d_in[1];
    const float* b1 = (const float*)d_in[2];
    const float* W2 = (const float*)d_in[3];
    const float* b2 = (const float*)d_in[4];
    const float* Wc = (const float*)d_in[5];
    const float* bc = (const float*)d_in[6];
    const void*  ei = d_in[7];
    const void*  batch = d_in[8];

    int N = in_sizes[0] / 2;
    int E = in_sizes[7] / 2;
    int G = out_size / 3;

    // Workspace layout (descending alignment).
    float4* Q       = (float4*)d_ws;                       // [N]
    float*  B       = (float*)(Q + N);                     // [N,64]
    float2* T       = (float2*)(B + (size_t)N * H);        // [N]
    unsigned* packed = (unsigned*)(T + N);                 // [E]
    unsigned* binned = packed + E;                         // [E]
    unsigned short* csr16 = (unsigned short*)(binned + E); // [E]
    int*    counts  = (int*)(csr16 + ((E + 1) & ~1));      // [N]
    int*    offsets = counts + N;                          // [N+1]
    int*    bbase   = offsets + N + 1;                     // [NB+1]
    int*    bcur    = bbase + NB + 1;                      // [NB]
    float*  stats   = (float*)(bcur + NB);                 // [8]
    int*    bcnt    = (int*)(stats + 8);                   // [NB]
    int*    flags   = bcnt + NB;                           // [2]

    float* out = (float*)d_out;

    int nblk_n256 = (N + 255) / 256;

    // Zero stats + bcnt in one contiguous memset (flags written by k_stats).
    hipMemsetAsync(stats, 0, (8 + NB) * sizeof(float), stream);

    k_stats<<<128, 256, 0, stream>>>(x, N, stats, (const int*)ei, in_sizes[7],
                                     (const int*)batch, in_sizes[8], flags);

    // CSR build: pack+histogram, bucket scan, coarse scatter, bucket sort.
    k_count<<<256, 256, 0, stream>>>(ei, E, packed, bcnt, flags);
    k_bscan<<<1, NB, 0, stream>>>(bcnt, bbase, bcur, offsets, N, E);
    k_bscatter<<<2048, 256, 0, stream>>>(packed, bcur, binned, E);
    k_bsort<<<NB, NB, 0, stream>>>(binned, bbase, csr16, counts, offsets, N);

    // Layer 1 (pre-scaled rank-2 aggregation) -> Q table
    k_prepT<<<nblk_n256, 256, 0, stream>>>(x, stats, counts, T, N);
    k_aggQ<<<nblk_n256, 256, 0, stream>>>(csr16, offsets, T, counts, Q, N);

    // Layer 2: fused aggregation + GEMM + bias + relu
    k_gathgemm<<<(N + 63) / 64, 256, 0, stream>>>(csr16, offsets, Q, W1, b1,
                                                  W2, b2, B, N);

    // Pool + classify (sorted batch, inline search)
    k_poolcls<<<(G * H + 255) / 256, 256, 0, stream>>>(B, batch, Wc, bc, out,
                                                       N, G, flags);
}

// Round 13
// 129.520 us; speedup vs baseline: 9.3650x; 9.3650x over previous
//
#include <hip/hip_runtime.h>
#include <math.h>

// ---------------------------------------------------------------------------
// GaitGraph: standardize -> GCN(2->64)+ReLU -> GCN(64->64)+ReLU -> mean-pool
//            -> linear 64->3.   N=50000, E=800000, G=2048, H=64.
// R1: dst-CSR + pull-gather (585 -> 327us).
// R4: rank-2 layer-1 collapse + reg-tile GEMM + sorted pooling (-> 237us).
// R6/R7: layer-2 GEMM/agg swap + gemmB spill fix (-> 187us).
// R8/R9: u16 CSR + fused gathgemm w/ contiguous-range LDS-broadcast (-> 181us).
// R10: coarse scatter via 256 GLOBAL atomic cursors -> device-wide atomic
//      hotspot, 1090us (VALUBusy 0.15%). REVERTED.
// R11: atomic-free radix partition: per-block histograms (histM[bucket][blk])
//      + matrix exclusive scan gives each block private precomputed cursors;
//      k_part uses LDS-local cursors only. Then per-bucket LDS counting sort.
// R12/R13: identical resubmits (benches died to container failures).
// ---------------------------------------------------------------------------

#define H 64
#define NB 256
#define NBLK 256

__device__ __forceinline__ float nan0(float v) {
    return isfinite(v) ? v : 0.0f;
}

// Load index i from a buffer that is either int32 or int64 (flag is64).
__device__ __forceinline__ int ld_idx(const void* p, long long i, int is64) {
    if (is64) return (int)((const long long*)p)[i];
    return ((const int*)p)[i];
}

// Column sums + sumsq of the 2 input features (with nan_to_num).
// Block 0 additionally detects int64 vs int32 for edge_index and batch
// (odd int32 words all zero => int64 high words).
__global__ void k_stats(const float* __restrict__ x, int N,
                        float* __restrict__ stats,
                        const int* ei, int nEi, const int* batch, int nB,
                        int* flags) {
    if (blockIdx.x == 0) {
        __shared__ int nz_e, nz_b;
        if (threadIdx.x == 0) { nz_e = 0; nz_b = 0; }
        __syncthreads();
        int i = threadIdx.x;  // 0..255
        long long pe = 1 + 2 * ((long long)i * ((nEi - 2) / 2) / 256);
        if (pe < nEi && ei[pe] != 0) nz_e = 1;
        long long pb = 1 + 2 * ((long long)i * ((nB - 2) / 2) / 256);
        if (pb < nB && batch[pb] != 0) nz_b = 1;
        __syncthreads();
        if (threadIdx.x == 0) {
            flags[0] = (nz_e == 0);
            flags[1] = (nz_b == 0);
        }
    }
    float s0 = 0, s1 = 0, q0 = 0, q1 = 0;
    int tid = blockIdx.x * blockDim.x + threadIdx.x;
    int stride = gridDim.x * blockDim.x;
    for (int n = tid; n < N; n += stride) {
        float2 v = reinterpret_cast<const float2*>(x)[n];
        float a = nan0(v.x), b = nan0(v.y);
        s0 += a; s1 += b; q0 += a * a; q1 += b * b;
    }
    for (int m = 32; m >= 1; m >>= 1) {
        s0 += __shfl_down(s0, m);
        s1 += __shfl_down(s1, m);
        q0 += __shfl_down(q0, m);
        q1 += __shfl_down(q1, m);
    }
    __shared__ float red[4][4];
    int w = threadIdx.x >> 6, lane = threadIdx.x & 63;
    if (lane == 0) { red[w][0] = s0; red[w][1] = s1; red[w][2] = q0; red[w][3] = q1; }
    __syncthreads();
    if (threadIdx.x == 0) {
        int nw = blockDim.x >> 6;
        float t0 = 0, t1 = 0, t2 = 0, t3 = 0;
        for (int i = 0; i < nw; i++) {
            t0 += red[i][0]; t1 += red[i][1]; t2 += red[i][2]; t3 += red[i][3];
        }
        atomicAdd(&stats[0], t0);
        atomicAdd(&stats[1], t1);
        atomicAdd(&stats[2], t2);
        atomicAdd(&stats[3], t3);
    }
}

// Pack edges (dst<<16|src) + per-block coarse-bucket histogram.
// histM[bucket * NBLK + blk] = count of bucket entries in block blk's chunk.
__global__ __launch_bounds__(256) void k_hist(const void* ei, int E,
                                              unsigned* __restrict__ packed,
                                              int* __restrict__ histM,
                                              const int* __restrict__ flags) {
    __shared__ int hist[NB];
    for (int i = threadIdx.x; i < NB; i += 256) hist[i] = 0;
    __syncthreads();
    int is64 = flags[0];
    int blk = blockIdx.x;
    int beg = (int)((long long)blk * E / NBLK);
    int end = (int)((long long)(blk + 1) * E / NBLK);
    for (int e = beg + threadIdx.x; e < end; e += 256) {
        unsigned s = (unsigned)ld_idx(ei, e, is64);
        unsigned d = (unsigned)ld_idx(ei, (long long)E + e, is64);
        packed[e] = (d << 16) | s;
        atomicAdd(&hist[d >> 8], 1);
    }
    __syncthreads();
    for (int i = threadIdx.x; i < NB; i += 256)
        histM[i * NBLK + blk] = hist[i];
}

// scanA: block b = bucket b; exclusive scan of histM[b*NBLK .. +NBLK) in
// place; bucket total -> bsum[b].
__global__ __launch_bounds__(256) void k_scanA(int* __restrict__ histM,
                                               int* __restrict__ bsum) {
    __shared__ int tmp[NBLK];
    int f = blockIdx.x * NBLK + threadIdx.x;
    int v = histM[f];
    tmp[threadIdx.x] = v;
    __syncthreads();
    for (int off = 1; off < NBLK; off <<= 1) {
        int t = (threadIdx.x >= off) ? tmp[threadIdx.x - off] : 0;
        __syncthreads();
        tmp[threadIdx.x] += t;
        __syncthreads();
    }
    histM[f] = tmp[threadIdx.x] - v;
    if (threadIdx.x == NBLK - 1) bsum[blockIdx.x] = tmp[NBLK - 1];
}

// scanB: exclusive scan of the 256 bucket totals in place.
__global__ void k_scanB(int* __restrict__ bsum) {
    __shared__ int tmp[NB];
    int v = bsum[threadIdx.x];
    tmp[threadIdx.x] = v;
    __syncthreads();
    for (int off = 1; off < NB; off <<= 1) {
        int t = (threadIdx.x >= off) ? tmp[threadIdx.x - off] : 0;
        __syncthreads();
        tmp[threadIdx.x] += t;
        __syncthreads();
    }
    bsum[threadIdx.x] = tmp[threadIdx.x] - v;
}

// scanC: add bucket bases into histM (global cursor per (bucket, blk));
// emit bbase + sentinels.
__global__ __launch_bounds__(256) void k_scanC(int* __restrict__ histM,
                                               const int* __restrict__ bsum,
                                               int* __restrict__ bbase,
                                               int* __restrict__ offsets,
                                               int N, int E) {
    int b = blockIdx.x;
    int f = b * NBLK + threadIdx.x;
    histM[f] += bsum[b];
    if (threadIdx.x == 0) bbase[b] = bsum[b];
    if (f == 0) { bbase[NB] = E; offsets[N] = E; }
}

// Atomic-free partition: block blk re-reads its chunk; cursors for its 256
// buckets live in LDS (intra-block contention only); writes per bucket are
// contiguous sub-segments.
__global__ __launch_bounds__(256) void k_part(const unsigned* __restrict__ packed,
                                              const int* __restrict__ histM,
                                              unsigned* __restrict__ binned,
                                              int E) {
    __shared__ int cur[NB];
    int blk = blockIdx.x;
    for (int i = threadIdx.x; i < NB; i += 256) cur[i] = histM[i * NBLK + blk];
    __syncthreads();
    int beg = (int)((long long)blk * E / NBLK);
    int end = (int)((long long)(blk + 1) * E / NBLK);
    for (int e = beg + threadIdx.x; e < end; e += 256) {
        unsigned p = packed[e];
        int pos = atomicAdd(&cur[p >> 24], 1);  // LDS atomic
        binned[pos] = p;
    }
}

// Per-bucket counting sort: one block per bucket (256 local dst slots).
// Emits final csr16 segment + per-node degree counts + CSR offsets.
__global__ __launch_bounds__(256) void k_bsort(
    const unsigned* __restrict__ binned, const int* __restrict__ bbase,
    unsigned short* __restrict__ csr16, int* __restrict__ counts,
    int* __restrict__ offsets, int N) {
    __shared__ int hist[NB], tmp[NB], cur[NB];
    int b = blockIdx.x;
    int beg = bbase[b], end = bbase[b + 1];
    hist[threadIdx.x] = 0;
    __syncthreads();
    for (int i = beg + threadIdx.x; i < end; i += 256)
        atomicAdd(&hist[(binned[i] >> 16) & 0xff], 1);
    __syncthreads();
    int v = hist[threadIdx.x];
    tmp[threadIdx.x] = v;
    __syncthreads();
    for (int off = 1; off < NB; off <<= 1) {
        int t = (threadIdx.x >= off) ? tmp[threadIdx.x - off] : 0;
        __syncthreads();
        tmp[threadIdx.x] += t;
        __syncthreads();
    }
    int ex = tmp[threadIdx.x] - v;
    cur[threadIdx.x] = ex;
    int n = b * NB + threadIdx.x;
    if (n < N) { counts[n] = v; offsets[n] = beg + ex; }
    __syncthreads();
    for (int i = beg + threadIdx.x; i < end; i += 256) {
        unsigned p = binned[i];
        int t = atomicAdd(&cur[(p >> 16) & 0xff], 1);
        csr16[beg + t] = (unsigned short)(p & 0xffffu);
    }
}

// T[n] = dinv[n] * standardized x[n]  (stats-derived constants inline).
__global__ void k_prepT(const float* __restrict__ x,
                        const float* __restrict__ stats,
                        const int* __restrict__ counts,
                        float2* __restrict__ T, int N) {
    int n = blockIdx.x * blockDim.x + threadIdx.x;
    if (n >= N) return;
    float sum0 = stats[0], sum1 = stats[1], q0 = stats[2], q1 = stats[3];
    float mu0 = sum0 / N, mu1 = sum1 / N;
    float v0 = fmaxf((q0 - sum0 * sum0 / N) / (N - 1), 0.0f);
    float v1 = fmaxf((q1 - sum1 * sum1 / N) / (N - 1), 0.0f);
    float r0 = 1.0f / (sqrtf(v0) + 1e-6f);
    float r1 = 1.0f / (sqrtf(v1) + 1e-6f);
    float di = rsqrtf((float)(counts[n] + 1));
    float2 xv = reinterpret_cast<const float2*>(x)[n];
    T[n] = make_float2(di * (nan0(xv.x) - mu0) * r0,
                       di * (nan0(xv.y) - mu1) * r1);
}

// Layer-1 aggregation on pre-scaled T: S[d] = di*(sum_e T[s] + T[d]).
// Emits Q[n] = (S0*di, S1*di, di, 0) for the layer-2 gather.
__global__ void k_aggQ(const unsigned short* __restrict__ csr16,
                       const int* __restrict__ offsets,
                       const float2* __restrict__ T,
                       const int* __restrict__ counts,
                       float4* __restrict__ Q, int N) {
    int n = blockIdx.x * blockDim.x + threadIdx.x;
    if (n >= N) return;
    float di = rsqrtf((float)(counts[n] + 1));
    float2 t = T[n];
    float s0 = t.x, s1 = t.y;  // self term (already dinv-scaled)
    int beg = offsets[n], end = offsets[n + 1];
    for (int k = beg; k < end; k++) {
        float2 ts = T[csr16[k]];
        s0 += ts.x; s1 += ts.y;
    }
    Q[n] = make_float4(s0 * di * di, s1 * di * di, di, 0.0f);
}

// Fused layer-2 aggregation + GEMM + bias + relu.
// Block = 64 dst rows, 256 threads; wave w owns rows [w*16, w*16+16), whose
// edges are one CONTIGUOUS u16-CSR range. Phase 1: flat 64-edge chunks:
// full-width gather of Q entries into a per-wave LDS chunk, then per edge one
// broadcast ds_read_b128 + 5 VALU (relu pos-homogeneity folds the edge weight
// into Q). Phase 2: register-tile GEMM @W2+b2+relu.
__global__ __launch_bounds__(256, 4) void k_gathgemm(
    const unsigned short* __restrict__ csr16, const int* __restrict__ offsets,
    const float4* __restrict__ Q, const float* __restrict__ W1,
    const float* __restrict__ b1, const float* __restrict__ W2,
    const float* __restrict__ b2, float* __restrict__ Bout, int N) {
    __shared__ float At[64][68];      // At[j][r] = aggY[r][j], pitch 68
    __shared__ float Ws[64][64];
    __shared__ float bs[64];
    __shared__ float4 chunkW[4][64];  // per-wave gathered Q entries
    int tid = threadIdx.x;
    for (int i = tid; i < 64 * 64; i += 256) Ws[i >> 6][i & 63] = W2[i];
    if (tid < 64) bs[tid] = b2[tid];
    int rbase = blockIdx.x * 64;
    int wid = tid >> 6, j = tid & 63;
    float w10 = W1[j], w11 = W1[H + j], bb = b1[j];

    int r0 = min(rbase + wid * 16, N);
    int r1 = min(r0 + 16, N);
    if (r0 < r1) {
        int eEnd = offsets[r1];
        int row = r0;
        int rowEnd = offsets[row + 1];
        float4 qd = Q[row];
        float di = qd.z;
        float acc = fmaxf(qd.x * w10 + qd.y * w11 + qd.z * bb, 0.0f);  // self
        for (int base = offsets[r0]; base < eEnd; base += 64) {
            if (base + j < eEnd) chunkW[wid][j] = Q[csr16[base + j]];
            int cnt = min(64, eEnd - base);
            for (int k = 0; k < cnt; k++) {
                int ecur = base + k;            // wave-uniform
                while (ecur >= rowEnd) {        // row(s) complete
                    At[j][row - rbase] = di * acc;
                    row++;
                    rowEnd = offsets[row + 1];
                    qd = Q[row];
                    di = qd.z;
                    acc = fmaxf(qd.x * w10 + qd.y * w11 + qd.z * bb, 0.0f);
                }
                float4 q = chunkW[wid][k];      // LDS broadcast read
                acc += fmaxf(q.x * w10 + q.y * w11 + q.z * bb, 0.0f);
            }
        }
        while (row < r1) {
            At[j][row - rbase] = di * acc;
            row++;
            if (row < r1) {
                rowEnd = offsets[row + 1];
                qd = Q[row];
                di = qd.z;
                acc = fmaxf(qd.x * w10 + qd.y * w11 + qd.z * bb, 0.0f);
            }
        }
    }
    __syncthreads();
    int rg = (tid & 15) * 4;  // row group
    int cg = (tid >> 4) * 4;  // col group
    float acc2[4][4] = {{0}};
#pragma unroll 8
    for (int k = 0; k < 64; k++) {
        float4 a = *reinterpret_cast<const float4*>(&At[k][rg]);
        float4 b = *reinterpret_cast<const float4*>(&Ws[k][cg]);
        acc2[0][0] += a.x * b.x; acc2[0][1] += a.x * b.y;
        acc2[0][2] += a.x * b.z; acc2[0][3] += a.x * b.w;
        acc2[1][0] += a.y * b.x; acc2[1][1] += a.y * b.y;
        acc2[1][2] += a.y * b.z; acc2[1][3] += a.y * b.w;
        acc2[2][0] += a.z * b.x; acc2[2][1] += a.z * b.y;
        acc2[2][2] += a.z * b.z; acc2[2][3] += a.z * b.w;
        acc2[3][0] += a.w * b.x; acc2[3][1] += a.w * b.y;
        acc2[3][2] += a.w * b.z; acc2[3][3] += a.w * b.w;
    }
#pragma unroll
    for (int i2 = 0; i2 < 4; i2++) {
        int r = rbase + rg + i2;
        if (r < N) {
            *reinterpret_cast<float4*>(&Bout[(size_t)r * H + cg]) = make_float4(
                fmaxf(acc2[i2][0] + bs[cg + 0], 0.0f),
                fmaxf(acc2[i2][1] + bs[cg + 1], 0.0f),
                fmaxf(acc2[i2][2] + bs[cg + 2], 0.0f),
                fmaxf(acc2[i2][3] + bs[cg + 3], 0.0f));
        }
    }
}

// Mean-pool per graph (sorted batch; inline binary search) + 64x3 classify.
__global__ __launch_bounds__(256) void k_poolcls(
    const float* __restrict__ B, const void* batch,
    const float* __restrict__ Wc, const float* __restrict__ bc,
    float* __restrict__ out, int N, int G, const int* __restrict__ flags) {
    int t = blockIdx.x * blockDim.x + threadIdx.x;
    int g = t >> 6, j = t & 63;
    if (g >= G) return;
    int is64 = flags[1];
    int beg, end;
    {
        int lo = 0, hi = N;
        while (lo < hi) {
            int mid = (lo + hi) >> 1;
            if (ld_idx(batch, mid, is64) < g) lo = mid + 1; else hi = mid;
        }
        beg = lo;
    }
    {
        int lo = beg, hi = N;
        while (lo < hi) {
            int mid = (lo + hi) >> 1;
            if (ld_idx(batch, mid, is64) < g + 1) lo = mid + 1; else hi = mid;
        }
        end = lo;
    }
    float acc = 0.0f;
    for (int n = beg; n < end; n++) acc += B[(size_t)n * H + j];
    float p = acc / (float)max(end - beg, 1);
#pragma unroll
    for (int c = 0; c < 3; c++) {
        float v = p * Wc[j * 3 + c];
        for (int m = 32; m >= 1; m >>= 1) v += __shfl_xor(v, m);
        if (j == 0) out[g * 3 + c] = v + bc[c];
    }
}

extern "C" void kernel_launch(void* const* d_in, const int* in_sizes, int n_in,
                              void* d_out, int out_size, void* d_ws,
                              size_t ws_size, hipStream_t stream) {
    const float* x  = (const float*)d_in[0];
    const float* W1 = (const float*)d_in[1];
    const float* b1 = (const float*)d_in[2];
    const float* W2 = (const float*)d_in[3];
    const float* b2 = (const float*)d_in[4];
    const float* Wc = (const float*)d_in[5];
    const float* bc = (const float*)d_in[6];
    const void*  ei = d_in[7];
    const void*  batch = d_in[8];

    int N = in_sizes[0] / 2;
    int E = in_sizes[7] / 2;
    int G = out_size / 3;

    // Workspace layout (descending alignment).
    float4* Q       = (float4*)d_ws;                       // [N]
    float*  B       = (float*)(Q + N);                     // [N,64]
    float2* T       = (float2*)(B + (size_t)N * H);        // [N]
    unsigned* packed = (unsigned*)(T + N);                 // [E]
    unsigned* binned = packed + E;                         // [E]
    unsigned short* csr16 = (unsigned short*)(binned + E); // [E]
    int*    histM   = (int*)(csr16 + ((E + 1) & ~1));      // [NB*NBLK]
    int*    counts  = histM + NB * NBLK;                   // [N]
    int*    offsets = counts + N;                          // [N+1]
    int*    bbase   = offsets + N + 1;                     // [NB+1]
    int*    bsum    = bbase + NB + 1;                      // [NB]
    float*  stats   = (float*)(bsum + NB);                 // [8]
    int*    flags   = (int*)(stats + 8);                   // [2]

    float* out = (float*)d_out;

    int nblk_n256 = (N + 255) / 256;

    hipMemsetAsync(stats, 0, 8 * sizeof(float), stream);

    k_stats<<<128, 256, 0, stream>>>(x, N, stats, (const int*)ei, in_sizes[7],
                                     (const int*)batch, in_sizes[8], flags);

    // CSR build: atomic-free radix partition + per-bucket counting sort.
    k_hist<<<NBLK, 256, 0, stream>>>(ei, E, packed, histM, flags);
    k_scanA<<<NB, NBLK, 0, stream>>>(histM, bsum);
    k_scanB<<<1, NB, 0, stream>>>(bsum);
    k_scanC<<<NB, NBLK, 0, stream>>>(histM, bsum, bbase, offsets, N, E);
    k_part<<<NBLK, 256, 0, stream>>>(packed, histM, binned, E);
    k_bsort<<<NB, NB, 0, stream>>>(binned, bbase, csr16, counts, offsets, N);

    // Layer 1 (pre-scaled rank-2 aggregation) -> Q table
    k_prepT<<<nblk_n256, 256, 0, stream>>>(x, stats, counts, T, N);
    k_aggQ<<<nblk_n256, 256, 0, stream>>>(csr16, offsets, T, counts, Q, N);

    // Layer 2: fused aggregation + GEMM + bias + relu
    k_gathgemm<<<(N + 63) / 64, 256, 0, stream>>>(csr16, offsets, Q, W1, b1,
                                                  W2, b2, B, N);

    // Pool + classify (sorted batch, inline search)
    k_poolcls<<<(G * H + 255) / 256, 256, 0, stream>>>(B, batch, Wc, bc, out,
                                                       N, G, flags);
}

// Round 14
// 125.445 us; speedup vs baseline: 9.6693x; 1.0325x over previous
//
#include <hip/hip_runtime.h>
#include <math.h>

// ---------------------------------------------------------------------------
// GaitGraph: standardize -> GCN(2->64)+ReLU -> GCN(64->64)+ReLU -> mean-pool
//            -> linear 64->3.   N=50000, E=800000, G=2048, H=64.
// R1: dst-CSR + pull-gather (585 -> 327us).
// R4: rank-2 layer-1 collapse + reg-tile GEMM + sorted pooling (-> 237us).
// R6/R7: layer-2 GEMM/agg swap + gemmB spill fix (-> 187us).
// R8/R9: u16 CSR + fused gathgemm w/ contiguous-range LDS-broadcast (-> 181us).
// R10: global-cursor scatter -> atomic hotspot (1090us). REVERTED.
// R11/R13: atomic-free radix partition (histM + matrix scan + LDS cursors)
//          + per-bucket counting sort (-> 129.5us).
// R14: k_gathgemm latency-bound (44us, VALUBusy 37%, 12 waves/CU, chunk-gather
//      stall): 512-thread blocks (8 waves x 8 rows, 24 waves/CU) + double-
//      buffered chunk gather (global loads issued before processing previous
//      chunk). k_aggQ 4-lanes-per-node (3->12 waves/CU). prepT folded into
//      k_bsort.
// ---------------------------------------------------------------------------

#define H 64
#define NB 256
#define NBLK 256

__device__ __forceinline__ float nan0(float v) {
    return isfinite(v) ? v : 0.0f;
}

// Load index i from a buffer that is either int32 or int64 (flag is64).
__device__ __forceinline__ int ld_idx(const void* p, long long i, int is64) {
    if (is64) return (int)((const long long*)p)[i];
    return ((const int*)p)[i];
}

// Column sums + sumsq of the 2 input features (with nan_to_num).
// Block 0 additionally detects int64 vs int32 for edge_index and batch
// (odd int32 words all zero => int64 high words).
__global__ void k_stats(const float* __restrict__ x, int N,
                        float* __restrict__ stats,
                        const int* ei, int nEi, const int* batch, int nB,
                        int* flags) {
    if (blockIdx.x == 0) {
        __shared__ int nz_e, nz_b;
        if (threadIdx.x == 0) { nz_e = 0; nz_b = 0; }
        __syncthreads();
        int i = threadIdx.x;  // 0..255
        long long pe = 1 + 2 * ((long long)i * ((nEi - 2) / 2) / 256);
        if (pe < nEi && ei[pe] != 0) nz_e = 1;
        long long pb = 1 + 2 * ((long long)i * ((nB - 2) / 2) / 256);
        if (pb < nB && batch[pb] != 0) nz_b = 1;
        __syncthreads();
        if (threadIdx.x == 0) {
            flags[0] = (nz_e == 0);
            flags[1] = (nz_b == 0);
        }
    }
    float s0 = 0, s1 = 0, q0 = 0, q1 = 0;
    int tid = blockIdx.x * blockDim.x + threadIdx.x;
    int stride = gridDim.x * blockDim.x;
    for (int n = tid; n < N; n += stride) {
        float2 v = reinterpret_cast<const float2*>(x)[n];
        float a = nan0(v.x), b = nan0(v.y);
        s0 += a; s1 += b; q0 += a * a; q1 += b * b;
    }
    for (int m = 32; m >= 1; m >>= 1) {
        s0 += __shfl_down(s0, m);
        s1 += __shfl_down(s1, m);
        q0 += __shfl_down(q0, m);
        q1 += __shfl_down(q1, m);
    }
    __shared__ float red[4][4];
    int w = threadIdx.x >> 6, lane = threadIdx.x & 63;
    if (lane == 0) { red[w][0] = s0; red[w][1] = s1; red[w][2] = q0; red[w][3] = q1; }
    __syncthreads();
    if (threadIdx.x == 0) {
        int nw = blockDim.x >> 6;
        float t0 = 0, t1 = 0, t2 = 0, t3 = 0;
        for (int i = 0; i < nw; i++) {
            t0 += red[i][0]; t1 += red[i][1]; t2 += red[i][2]; t3 += red[i][3];
        }
        atomicAdd(&stats[0], t0);
        atomicAdd(&stats[1], t1);
        atomicAdd(&stats[2], t2);
        atomicAdd(&stats[3], t3);
    }
}

// Pack edges (dst<<16|src) + per-block coarse-bucket histogram.
// histM[bucket * NBLK + blk] = count of bucket entries in block blk's chunk.
__global__ __launch_bounds__(256) void k_hist(const void* ei, int E,
                                              unsigned* __restrict__ packed,
                                              int* __restrict__ histM,
                                              const int* __restrict__ flags) {
    __shared__ int hist[NB];
    for (int i = threadIdx.x; i < NB; i += 256) hist[i] = 0;
    __syncthreads();
    int is64 = flags[0];
    int blk = blockIdx.x;
    int beg = (int)((long long)blk * E / NBLK);
    int end = (int)((long long)(blk + 1) * E / NBLK);
    for (int e = beg + threadIdx.x; e < end; e += 256) {
        unsigned s = (unsigned)ld_idx(ei, e, is64);
        unsigned d = (unsigned)ld_idx(ei, (long long)E + e, is64);
        packed[e] = (d << 16) | s;
        atomicAdd(&hist[d >> 8], 1);
    }
    __syncthreads();
    for (int i = threadIdx.x; i < NB; i += 256)
        histM[i * NBLK + blk] = hist[i];
}

// scanA: block b = bucket b; exclusive scan of histM[b*NBLK .. +NBLK) in
// place; bucket total -> bsum[b].
__global__ __launch_bounds__(256) void k_scanA(int* __restrict__ histM,
                                               int* __restrict__ bsum) {
    __shared__ int tmp[NBLK];
    int f = blockIdx.x * NBLK + threadIdx.x;
    int v = histM[f];
    tmp[threadIdx.x] = v;
    __syncthreads();
    for (int off = 1; off < NBLK; off <<= 1) {
        int t = (threadIdx.x >= off) ? tmp[threadIdx.x - off] : 0;
        __syncthreads();
        tmp[threadIdx.x] += t;
        __syncthreads();
    }
    histM[f] = tmp[threadIdx.x] - v;
    if (threadIdx.x == NBLK - 1) bsum[blockIdx.x] = tmp[NBLK - 1];
}

// scanB: exclusive scan of the 256 bucket totals in place.
__global__ void k_scanB(int* __restrict__ bsum) {
    __shared__ int tmp[NB];
    int v = bsum[threadIdx.x];
    tmp[threadIdx.x] = v;
    __syncthreads();
    for (int off = 1; off < NB; off <<= 1) {
        int t = (threadIdx.x >= off) ? tmp[threadIdx.x - off] : 0;
        __syncthreads();
        tmp[threadIdx.x] += t;
        __syncthreads();
    }
    bsum[threadIdx.x] = tmp[threadIdx.x] - v;
}

// scanC: add bucket bases into histM (global cursor per (bucket, blk));
// emit bbase + sentinels.
__global__ __launch_bounds__(256) void k_scanC(int* __restrict__ histM,
                                               const int* __restrict__ bsum,
                                               int* __restrict__ bbase,
                                               int* __restrict__ offsets,
                                               int N, int E) {
    int b = blockIdx.x;
    int f = b * NBLK + threadIdx.x;
    histM[f] += bsum[b];
    if (threadIdx.x == 0) bbase[b] = bsum[b];
    if (f == 0) { bbase[NB] = E; offsets[N] = E; }
}

// Atomic-free partition: block blk re-reads its chunk; cursors for its 256
// buckets live in LDS (intra-block contention only); writes per bucket are
// contiguous sub-segments.
__global__ __launch_bounds__(256) void k_part(const unsigned* __restrict__ packed,
                                              const int* __restrict__ histM,
                                              unsigned* __restrict__ binned,
                                              int E) {
    __shared__ int cur[NB];
    int blk = blockIdx.x;
    for (int i = threadIdx.x; i < NB; i += 256) cur[i] = histM[i * NBLK + blk];
    __syncthreads();
    int beg = (int)((long long)blk * E / NBLK);
    int end = (int)((long long)(blk + 1) * E / NBLK);
    for (int e = beg + threadIdx.x; e < end; e += 256) {
        unsigned p = packed[e];
        int pos = atomicAdd(&cur[p >> 24], 1);  // LDS atomic
        binned[pos] = p;
    }
}

// Per-bucket counting sort: one block per bucket (256 local dst slots).
// Emits final csr16 segment + per-node degree counts + CSR offsets + the
// pre-scaled feature table T[n] (prepT folded in; stats already final).
__global__ __launch_bounds__(256) void k_bsort(
    const unsigned* __restrict__ binned, const int* __restrict__ bbase,
    unsigned short* __restrict__ csr16, int* __restrict__ counts,
    int* __restrict__ offsets, const float* __restrict__ x,
    const float* __restrict__ stats, float2* __restrict__ T, int N) {
    __shared__ int hist[NB], tmp[NB], cur[NB];
    int b = blockIdx.x;
    int beg = bbase[b], end = bbase[b + 1];
    hist[threadIdx.x] = 0;
    __syncthreads();
    for (int i = beg + threadIdx.x; i < end; i += 256)
        atomicAdd(&hist[(binned[i] >> 16) & 0xff], 1);
    __syncthreads();
    int v = hist[threadIdx.x];
    tmp[threadIdx.x] = v;
    __syncthreads();
    for (int off = 1; off < NB; off <<= 1) {
        int t = (threadIdx.x >= off) ? tmp[threadIdx.x - off] : 0;
        __syncthreads();
        tmp[threadIdx.x] += t;
        __syncthreads();
    }
    int ex = tmp[threadIdx.x] - v;
    cur[threadIdx.x] = ex;
    int n = b * NB + threadIdx.x;
    if (n < N) {
        counts[n] = v;
        offsets[n] = beg + ex;
        // prepT: T[n] = dinv * standardized x[n]
        float sum0 = stats[0], sum1 = stats[1], q0 = stats[2], q1 = stats[3];
        float mu0 = sum0 / N, mu1 = sum1 / N;
        float v0 = fmaxf((q0 - sum0 * sum0 / N) / (N - 1), 0.0f);
        float v1 = fmaxf((q1 - sum1 * sum1 / N) / (N - 1), 0.0f);
        float r0 = 1.0f / (sqrtf(v0) + 1e-6f);
        float r1 = 1.0f / (sqrtf(v1) + 1e-6f);
        float di = rsqrtf((float)(v + 1));
        float2 xv = reinterpret_cast<const float2*>(x)[n];
        T[n] = make_float2(di * (nan0(xv.x) - mu0) * r0,
                           di * (nan0(xv.y) - mu1) * r1);
    }
    __syncthreads();
    for (int i = beg + threadIdx.x; i < end; i += 256) {
        unsigned p = binned[i];
        int t = atomicAdd(&cur[(p >> 16) & 0xff], 1);
        csr16[beg + t] = (unsigned short)(p & 0xffffu);
    }
}

// Layer-1 aggregation on pre-scaled T: S[d] = di*(sum_e T[s] + T[d]).
// 4 lanes per node (edge loop split 4 ways + shfl_xor reduce) for TLP.
// Emits Q[n] = (S0*di, S1*di, di, 0) for the layer-2 gather.
__global__ void k_aggQ(const unsigned short* __restrict__ csr16,
                       const int* __restrict__ offsets,
                       const float2* __restrict__ T,
                       const int* __restrict__ counts,
                       float4* __restrict__ Q, int N) {
    int t = blockIdx.x * blockDim.x + threadIdx.x;
    int n = t >> 2, sub = t & 3;
    if (n >= N) return;
    int beg = offsets[n], end = offsets[n + 1];
    float s0 = 0.0f, s1 = 0.0f;
    for (int k = beg + sub; k < end; k += 4) {
        float2 ts = T[csr16[k]];
        s0 += ts.x; s1 += ts.y;
    }
    s0 += __shfl_xor(s0, 1); s1 += __shfl_xor(s1, 1);
    s0 += __shfl_xor(s0, 2); s1 += __shfl_xor(s1, 2);
    if (sub == 0) {
        float di = rsqrtf((float)(counts[n] + 1));
        float2 tn = T[n];
        s0 += tn.x; s1 += tn.y;  // self term (already dinv-scaled)
        Q[n] = make_float4(s0 * di * di, s1 * di * di, di, 0.0f);
    }
}

// Fused layer-2 aggregation + GEMM + bias + relu.
// 512 threads = 8 waves; wave w owns rows [w*8, w*8+8) of the 64-row tile
// (contiguous u16-CSR range). Phase 1: flat 64-edge chunks with DOUBLE-
// BUFFERED gather: next chunk's Q loads issued into registers before
// processing the current chunk from LDS (global latency hidden under the
// ~64-edge broadcast-compute). Phase 2: register-tile GEMM @W2+b2+relu,
// 4 rows x 2 cols per thread, col-major lanes for coalesced stores.
__global__ __launch_bounds__(512, 6) void k_gathgemm(
    const unsigned short* __restrict__ csr16, const int* __restrict__ offsets,
    const float4* __restrict__ Q, const float* __restrict__ W1,
    const float* __restrict__ b1, const float* __restrict__ W2,
    const float* __restrict__ b2, float* __restrict__ Bout, int N) {
    __shared__ float At[64][68];        // At[j][r] = aggY[r][j], pitch 68
    __shared__ float Ws[64][64];
    __shared__ float bs[64];
    __shared__ float4 chunkW[8][2][64]; // per-wave double-buffered Q entries
    int tid = threadIdx.x;
    for (int i = tid; i < 64 * 64; i += 512) Ws[i >> 6][i & 63] = W2[i];
    if (tid < 64) bs[tid] = b2[tid];
    int rbase = blockIdx.x * 64;
    int wid = tid >> 6, j = tid & 63;
    float w10 = W1[j], w11 = W1[H + j], bb = b1[j];

    int r0 = min(rbase + wid * 8, N);
    int r1 = min(r0 + 8, N);
    if (r0 < r1) {
        int eBeg = offsets[r0], eEnd = offsets[r1];
        int row = r0;
        int rowEnd = offsets[row + 1];
        float4 qd = Q[row];
        float di = qd.z;
        float acc = fmaxf(qd.x * w10 + qd.y * w11 + qd.z * bb, 0.0f);  // self
        // prologue: gather chunk 0
        if (eBeg + j < eEnd) chunkW[wid][0][j] = Q[csr16[eBeg + j]];
        int buf = 0;
        for (int base = eBeg; base < eEnd; base += 64) {
            int nbase = base + 64;
            bool hasNext = nbase < eEnd;   // wave-uniform
            float4 qn;
            if (hasNext && nbase + j < eEnd) qn = Q[csr16[nbase + j]];
            int cnt = min(64, eEnd - base);
            for (int k = 0; k < cnt; k++) {
                int ecur = base + k;            // wave-uniform
                while (ecur >= rowEnd) {        // row(s) complete
                    At[j][row - rbase] = di * acc;
                    row++;
                    rowEnd = offsets[row + 1];
                    qd = Q[row];
                    di = qd.z;
                    acc = fmaxf(qd.x * w10 + qd.y * w11 + qd.z * bb, 0.0f);
                }
                float4 q = chunkW[wid][buf][k];  // LDS broadcast read
                acc += fmaxf(q.x * w10 + q.y * w11 + q.z * bb, 0.0f);
            }
            if (hasNext) {
                if (nbase + j < eEnd) chunkW[wid][buf ^ 1][j] = qn;
                buf ^= 1;
            }
        }
        // Flush remaining rows (incl. zero-degree tail).
        while (row < r1) {
            At[j][row - rbase] = di * acc;
            row++;
            if (row < r1) {
                rowEnd = offsets[row + 1];
                qd = Q[row];
                di = qd.z;
                acc = fmaxf(qd.x * w10 + qd.y * w11 + qd.z * bb, 0.0f);
            }
        }
    }
    __syncthreads();
    // Phase 2: thread -> 4 rows x 2 cols. Lanes ordered by col for coalesced
    // global stores; At reads are 2-address broadcasts, Ws reads 2-way.
    int rg = (tid >> 5) * 4;   // 0..60
    int cg = (tid & 31) * 2;   // 0..62
    float a2[4][2] = {{0.0f}};
#pragma unroll 8
    for (int k = 0; k < 64; k++) {
        float4 a = *reinterpret_cast<const float4*>(&At[k][rg]);
        float2 b = *reinterpret_cast<const float2*>(&Ws[k][cg]);
        a2[0][0] += a.x * b.x; a2[0][1] += a.x * b.y;
        a2[1][0] += a.y * b.x; a2[1][1] += a.y * b.y;
        a2[2][0] += a.z * b.x; a2[2][1] += a.z * b.y;
        a2[3][0] += a.w * b.x; a2[3][1] += a.w * b.y;
    }
#pragma unroll
    for (int i2 = 0; i2 < 4; i2++) {
        int r = rbase + rg + i2;
        if (r < N) {
            *reinterpret_cast<float2*>(&Bout[(size_t)r * H + cg]) = make_float2(
                fmaxf(a2[i2][0] + bs[cg + 0], 0.0f),
                fmaxf(a2[i2][1] + bs[cg + 1], 0.0f));
        }
    }
}

// Mean-pool per graph (sorted batch; inline binary search) + 64x3 classify.
__global__ __launch_bounds__(256) void k_poolcls(
    const float* __restrict__ B, const void* batch,
    const float* __restrict__ Wc, const float* __restrict__ bc,
    float* __restrict__ out, int N, int G, const int* __restrict__ flags) {
    int t = blockIdx.x * blockDim.x + threadIdx.x;
    int g = t >> 6, j = t & 63;
    if (g >= G) return;
    int is64 = flags[1];
    int beg, end;
    {
        int lo = 0, hi = N;
        while (lo < hi) {
            int mid = (lo + hi) >> 1;
            if (ld_idx(batch, mid, is64) < g) lo = mid + 1; else hi = mid;
        }
        beg = lo;
    }
    {
        int lo = beg, hi = N;
        while (lo < hi) {
            int mid = (lo + hi) >> 1;
            if (ld_idx(batch, mid, is64) < g + 1) lo = mid + 1; else hi = mid;
        }
        end = lo;
    }
    float acc = 0.0f;
    for (int n = beg; n < end; n++) acc += B[(size_t)n * H + j];
    float p = acc / (float)max(end - beg, 1);
#pragma unroll
    for (int c = 0; c < 3; c++) {
        float v = p * Wc[j * 3 + c];
        for (int m = 32; m >= 1; m >>= 1) v += __shfl_xor(v, m);
        if (j == 0) out[g * 3 + c] = v + bc[c];
    }
}

extern "C" void kernel_launch(void* const* d_in, const int* in_sizes, int n_in,
                              void* d_out, int out_size, void* d_ws,
                              size_t ws_size, hipStream_t stream) {
    const float* x  = (const float*)d_in[0];
    const float* W1 = (const float*)d_in[1];
    const float* b1 = (const float*)d_in[2];
    const float* W2 = (const float*)d_in[3];
    const float* b2 = (const float*)d_in[4];
    const float* Wc = (const float*)d_in[5];
    const float* bc = (const float*)d_in[6];
    const void*  ei = d_in[7];
    const void*  batch = d_in[8];

    int N = in_sizes[0] / 2;
    int E = in_sizes[7] / 2;
    int G = out_size / 3;

    // Workspace layout (descending alignment).
    float4* Q       = (float4*)d_ws;                       // [N]
    float*  B       = (float*)(Q + N);                     // [N,64]
    float2* T       = (float2*)(B + (size_t)N * H);        // [N]
    unsigned* packed = (unsigned*)(T + N);                 // [E]
    unsigned* binned = packed + E;                         // [E]
    unsigned short* csr16 = (unsigned short*)(binned + E); // [E]
    int*    histM   = (int*)(csr16 + ((E + 1) & ~1));      // [NB*NBLK]
    int*    counts  = histM + NB * NBLK;                   // [N]
    int*    offsets = counts + N;                          // [N+1]
    int*    bbase   = offsets + N + 1;                     // [NB+1]
    int*    bsum    = bbase + NB + 1;                      // [NB]
    float*  stats   = (float*)(bsum + NB);                 // [8]
    int*    flags   = (int*)(stats + 8);                   // [2]

    float* out = (float*)d_out;

    hipMemsetAsync(stats, 0, 8 * sizeof(float), stream);

    k_stats<<<128, 256, 0, stream>>>(x, N, stats, (const int*)ei, in_sizes[7],
                                     (const int*)batch, in_sizes[8], flags);

    // CSR build: atomic-free radix partition + per-bucket counting sort.
    k_hist<<<NBLK, 256, 0, stream>>>(ei, E, packed, histM, flags);
    k_scanA<<<NB, NBLK, 0, stream>>>(histM, bsum);
    k_scanB<<<1, NB, 0, stream>>>(bsum);
    k_scanC<<<NB, NBLK, 0, stream>>>(histM, bsum, bbase, offsets, N, E);
    k_part<<<NBLK, 256, 0, stream>>>(packed, histM, binned, E);
    k_bsort<<<NB, NB, 0, stream>>>(binned, bbase, csr16, counts, offsets,
                                   x, stats, T, N);

    // Layer 1 (pre-scaled rank-2 aggregation, 4 lanes/node) -> Q table
    k_aggQ<<<(N * 4 + 255) / 256, 256, 0, stream>>>(csr16, offsets, T, counts,
                                                    Q, N);

    // Layer 2: fused aggregation + GEMM + bias + relu (8 waves, dbuf gather)
    k_gathgemm<<<(N + 63) / 64, 512, 0, stream>>>(csr16, offsets, Q, W1, b1,
                                                  W2, b2, B, N);

    // Pool + classify (sorted batch, inline search)
    k_poolcls<<<(G * H + 255) / 256, 256, 0, stream>>>(B, batch, Wc, bc, out,
                                                       N, G, flags);
}

// Round 15
// 94.429 us; speedup vs baseline: 12.8452x; 1.3285x over previous
//
#include <hip/hip_runtime.h>
#include <math.h>

// ---------------------------------------------------------------------------
// GaitGraph: standardize -> GCN(2->64)+ReLU -> GCN(64->64)+ReLU -> mean-pool
//            -> linear 64->3.   N=50000, E=800000, G=2048, H=64.
// R1..R9: CSR pull-gather, rank-2 layer-1 collapse, layer-2 GEMM/agg swap,
//         u16 CSR, fused gathgemm (585 -> 181us).
// R10: global-cursor scatter -> atomic hotspot (1090us). REVERTED.
// R11/R13: atomic-free radix partition + bucket counting sort (-> 129.5us).
// R14: more waves + dbuf gather: k_gathgemm 44->45us (NULL). Diagnosis was
//      wrong: not wave-starved but serial-chain-bound (row-advance global
//      loads force vmcnt drains; per-edge ds_read not pipelineable).
// R15: (a) gathgemm: row metadata (offsets/Q) hoisted to per-wave LDS at
//          prologue -> edge loop is LDS/VALU only; edges processed 4-wide
//          (4 indep ds_reads + 4 indep relu temps, then register-only
//          boundary accumulates). (b) 11 -> 8 dispatches: stats+hist fused
//          (k_pre, local is64 detect), stats reduce folded into scanA blk0
//          (memset deleted), scanB folded into scanC. (c) poolcls 4-acc.
// ---------------------------------------------------------------------------

#define H 64
#define NB 256
#define NBLK 256

__device__ __forceinline__ float nan0(float v) {
    return isfinite(v) ? v : 0.0f;
}

// Load index i from a buffer that is either int32 or int64 (flag is64).
__device__ __forceinline__ int ld_idx(const void* p, long long i, int is64) {
    if (is64) return (int)((const long long*)p)[i];
    return ((const int*)p)[i];
}

// Fused: blocks [0,128) = feature stats partials (+ batch int64 detect in
// block 0); blocks [128,384) = edge pack + per-block bucket histogram with
// LOCAL int64 detection (odd int32 words of own chunk all zero => int64).
__global__ __launch_bounds__(256) void k_pre(
    const float* __restrict__ x, int N, float4* __restrict__ stats_part,
    const void* ei, int E, const int* batch, int nB, int* flags,
    unsigned* __restrict__ packed, int* __restrict__ histM) {
    if (blockIdx.x < 128) {
        // ---- stats path ----
        if (blockIdx.x == 0) {
            __shared__ int nz_b;
            if (threadIdx.x == 0) nz_b = 0;
            __syncthreads();
            long long pb = 1 + 2 * ((long long)threadIdx.x * ((nB - 2) / 2) / 256);
            if (pb < nB && batch[pb] != 0) nz_b = 1;
            __syncthreads();
            if (threadIdx.x == 0) flags[1] = (nz_b == 0);
        }
        float s0 = 0, s1 = 0, q0 = 0, q1 = 0;
        int tid = blockIdx.x * blockDim.x + threadIdx.x;
        int stride = 128 * blockDim.x;
        for (int n = tid; n < N; n += stride) {
            float2 v = reinterpret_cast<const float2*>(x)[n];
            float a = nan0(v.x), b = nan0(v.y);
            s0 += a; s1 += b; q0 += a * a; q1 += b * b;
        }
        for (int m = 32; m >= 1; m >>= 1) {
            s0 += __shfl_down(s0, m);
            s1 += __shfl_down(s1, m);
            q0 += __shfl_down(q0, m);
            q1 += __shfl_down(q1, m);
        }
        __shared__ float red[4][4];
        int w = threadIdx.x >> 6, lane = threadIdx.x & 63;
        if (lane == 0) { red[w][0] = s0; red[w][1] = s1; red[w][2] = q0; red[w][3] = q1; }
        __syncthreads();
        if (threadIdx.x == 0) {
            float t0 = 0, t1 = 0, t2 = 0, t3 = 0;
            for (int i = 0; i < 4; i++) {
                t0 += red[i][0]; t1 += red[i][1]; t2 += red[i][2]; t3 += red[i][3];
            }
            stats_part[blockIdx.x] = make_float4(t0, t1, t2, t3);
        }
    } else {
        // ---- hist path ----
        int blk = blockIdx.x - 128;
        int beg = (int)((long long)blk * E / NBLK);
        int end = (int)((long long)(blk + 1) * E / NBLK);
        __shared__ int hist[NB];
        __shared__ int nz_e;
        if (threadIdx.x == 0) nz_e = 0;
        for (int i = threadIdx.x; i < NB; i += 256) hist[i] = 0;
        __syncthreads();
        // local detection: sample odd int32 positions within own chunk
        if (threadIdx.x < 64) {
            int span = end - beg;
            long long p = 2LL * beg + 1 +
                          2 * ((long long)threadIdx.x * (span > 1 ? span - 1 : 0) / 64);
            if (((const int*)ei)[p] != 0) nz_e = 1;
        }
        __syncthreads();
        int is64 = (nz_e == 0);
        for (int e = beg + threadIdx.x; e < end; e += 256) {
            unsigned s = (unsigned)ld_idx(ei, e, is64);
            unsigned d = (unsigned)ld_idx(ei, (long long)E + e, is64);
            packed[e] = (d << 16) | s;
            atomicAdd(&hist[d >> 8], 1);
        }
        __syncthreads();
        for (int i = threadIdx.x; i < NB; i += 256)
            histM[i * NBLK + blk] = hist[i];
    }
}

// scanA: block b = bucket b; exclusive scan of histM[b*NBLK..+NBLK) in place;
// bucket total -> bsum[b]. Block 0 additionally reduces stats partials.
__global__ __launch_bounds__(256) void k_scanA(int* __restrict__ histM,
                                               int* __restrict__ bsum,
                                               const float4* __restrict__ stats_part,
                                               float* __restrict__ stats) {
    __shared__ int tmp[NBLK];
    int f = blockIdx.x * NBLK + threadIdx.x;
    int v = histM[f];
    tmp[threadIdx.x] = v;
    if (blockIdx.x == 0) {
        __shared__ float4 sred[128];
        if (threadIdx.x < 128) sred[threadIdx.x] = stats_part[threadIdx.x];
        __syncthreads();
        for (int off = 64; off >= 1; off >>= 1) {
            if (threadIdx.x < off) {
                sred[threadIdx.x].x += sred[threadIdx.x + off].x;
                sred[threadIdx.x].y += sred[threadIdx.x + off].y;
                sred[threadIdx.x].z += sred[threadIdx.x + off].z;
                sred[threadIdx.x].w += sred[threadIdx.x + off].w;
            }
            __syncthreads();
        }
        if (threadIdx.x == 0) *reinterpret_cast<float4*>(stats) = sred[0];
    } else {
        __syncthreads();  // match barrier counts not required across blocks
    }
    __syncthreads();
    for (int off = 1; off < NBLK; off <<= 1) {
        int t = (threadIdx.x >= off) ? tmp[threadIdx.x - off] : 0;
        __syncthreads();
        tmp[threadIdx.x] += t;
        __syncthreads();
    }
    histM[f] = tmp[threadIdx.x] - v;
    if (threadIdx.x == NBLK - 1) bsum[blockIdx.x] = tmp[NBLK - 1];
}

// scanC (with scanB folded in): every block redundantly scans the 256 bucket
// totals in LDS, then adds its bucket's base into histM; emits bbase +
// sentinels.
__global__ __launch_bounds__(256) void k_scanC(int* __restrict__ histM,
                                               const int* __restrict__ bsum,
                                               int* __restrict__ bbase,
                                               int* __restrict__ offsets,
                                               int N, int E) {
    __shared__ int tmp[NB];
    __shared__ int mybase;
    int v = bsum[threadIdx.x];
    tmp[threadIdx.x] = v;
    __syncthreads();
    for (int off = 1; off < NB; off <<= 1) {
        int t = (threadIdx.x >= off) ? tmp[threadIdx.x - off] : 0;
        __syncthreads();
        tmp[threadIdx.x] += t;
        __syncthreads();
    }
    if (threadIdx.x == blockIdx.x) mybase = tmp[threadIdx.x] - v;
    __syncthreads();
    int b = blockIdx.x;
    histM[b * NBLK + threadIdx.x] += mybase;
    if (threadIdx.x == 0) bbase[b] = mybase;
    if (b == 0 && threadIdx.x == 0) { bbase[NB] = E; offsets[N] = E; }
}

// Atomic-free partition: block blk re-reads its chunk; cursors for its 256
// buckets live in LDS; each (block,bucket) writes a contiguous sub-segment.
__global__ __launch_bounds__(256) void k_part(const unsigned* __restrict__ packed,
                                              const int* __restrict__ histM,
                                              unsigned* __restrict__ binned,
                                              int E) {
    __shared__ int cur[NB];
    int blk = blockIdx.x;
    for (int i = threadIdx.x; i < NB; i += 256) cur[i] = histM[i * NBLK + blk];
    __syncthreads();
    int beg = (int)((long long)blk * E / NBLK);
    int end = (int)((long long)(blk + 1) * E / NBLK);
    for (int e = beg + threadIdx.x; e < end; e += 256) {
        unsigned p = packed[e];
        int pos = atomicAdd(&cur[p >> 24], 1);  // LDS atomic
        binned[pos] = p;
    }
}

// Per-bucket counting sort + prepT. Emits csr16 segment, per-node degree
// counts, CSR offsets, and T[n] = dinv * standardized x[n].
__global__ __launch_bounds__(256) void k_bsort(
    const unsigned* __restrict__ binned, const int* __restrict__ bbase,
    unsigned short* __restrict__ csr16, int* __restrict__ counts,
    int* __restrict__ offsets, const float* __restrict__ x,
    const float* __restrict__ stats, float2* __restrict__ T, int N) {
    __shared__ int hist[NB], tmp[NB], cur[NB];
    int b = blockIdx.x;
    int beg = bbase[b], end = bbase[b + 1];
    hist[threadIdx.x] = 0;
    __syncthreads();
    for (int i = beg + threadIdx.x; i < end; i += 256)
        atomicAdd(&hist[(binned[i] >> 16) & 0xff], 1);
    __syncthreads();
    int v = hist[threadIdx.x];
    tmp[threadIdx.x] = v;
    __syncthreads();
    for (int off = 1; off < NB; off <<= 1) {
        int t = (threadIdx.x >= off) ? tmp[threadIdx.x - off] : 0;
        __syncthreads();
        tmp[threadIdx.x] += t;
        __syncthreads();
    }
    int ex = tmp[threadIdx.x] - v;
    cur[threadIdx.x] = ex;
    int n = b * NB + threadIdx.x;
    if (n < N) {
        counts[n] = v;
        offsets[n] = beg + ex;
        float sum0 = stats[0], sum1 = stats[1], q0 = stats[2], q1 = stats[3];
        float mu0 = sum0 / N, mu1 = sum1 / N;
        float v0 = fmaxf((q0 - sum0 * sum0 / N) / (N - 1), 0.0f);
        float v1 = fmaxf((q1 - sum1 * sum1 / N) / (N - 1), 0.0f);
        float r0 = 1.0f / (sqrtf(v0) + 1e-6f);
        float r1 = 1.0f / (sqrtf(v1) + 1e-6f);
        float di = rsqrtf((float)(v + 1));
        float2 xv = reinterpret_cast<const float2*>(x)[n];
        T[n] = make_float2(di * (nan0(xv.x) - mu0) * r0,
                           di * (nan0(xv.y) - mu1) * r1);
    }
    __syncthreads();
    for (int i = beg + threadIdx.x; i < end; i += 256) {
        unsigned p = binned[i];
        int t = atomicAdd(&cur[(p >> 16) & 0xff], 1);
        csr16[beg + t] = (unsigned short)(p & 0xffffu);
    }
}

// Layer-1 aggregation on pre-scaled T: 4 lanes per node + shfl_xor reduce.
// Emits Q[n] = (S0*di, S1*di, di, 0).
__global__ void k_aggQ(const unsigned short* __restrict__ csr16,
                       const int* __restrict__ offsets,
                       const float2* __restrict__ T,
                       const int* __restrict__ counts,
                       float4* __restrict__ Q, int N) {
    int t = blockIdx.x * blockDim.x + threadIdx.x;
    int n = t >> 2, sub = t & 3;
    if (n >= N) return;
    int beg = offsets[n], end = offsets[n + 1];
    float s0 = 0.0f, s1 = 0.0f;
    for (int k = beg + sub; k < end; k += 4) {
        float2 ts = T[csr16[k]];
        s0 += ts.x; s1 += ts.y;
    }
    s0 += __shfl_xor(s0, 1); s1 += __shfl_xor(s1, 1);
    s0 += __shfl_xor(s0, 2); s1 += __shfl_xor(s1, 2);
    if (sub == 0) {
        float di = rsqrtf((float)(counts[n] + 1));
        float2 tn = T[n];
        s0 += tn.x; s1 += tn.y;
        Q[n] = make_float4(s0 * di * di, s1 * di * di, di, 0.0f);
    }
}

// Fused layer-2 aggregation + GEMM + bias + relu.
// 512 threads = 8 waves; wave w owns rows [w*8, w*8+8). Row metadata
// (offsets[r+1], Q[r]) hoisted into per-wave LDS at prologue so the edge
// loop touches ONLY LDS+VALU (the once-per-chunk global gather is the sole
// vmem op). Edges processed 4-wide: 4 independent ds_read_b128 + 4 relu
// temps, then register-only boundary-checked accumulates.
__global__ __launch_bounds__(512, 6) void k_gathgemm(
    const unsigned short* __restrict__ csr16, const int* __restrict__ offsets,
    const float4* __restrict__ Q, const float* __restrict__ W1,
    const float* __restrict__ b1, const float* __restrict__ W2,
    const float* __restrict__ b2, float* __restrict__ Bout, int N) {
    __shared__ float At[64][68];        // At[j][r] = aggY[r][j]
    __shared__ float Ws[64][64];
    __shared__ float bs[64];
    __shared__ float4 chunkW[8][2][64]; // per-wave double-buffered Q entries
    __shared__ float4 qrow[8][8];       // per-wave row Q values
    __shared__ int    rend[8][8];       // per-wave row end offsets
    int tid = threadIdx.x;
    for (int i = tid; i < 64 * 64; i += 512) Ws[i >> 6][i & 63] = W2[i];
    if (tid < 64) bs[tid] = b2[tid];
    int rbase = blockIdx.x * 64;
    int wid = tid >> 6, j = tid & 63;
    float w10 = W1[j], w11 = W1[H + j], bb = b1[j];

    int r0 = min(rbase + wid * 8, N);
    int r1 = min(r0 + 8, N);
    if (r0 < r1) {
        // prologue: lanes 0..7 stash row metadata in LDS
        if (j < 8 && r0 + j < r1) {
            qrow[wid][j] = Q[r0 + j];
            rend[wid][j] = offsets[r0 + j + 1];
        }
        int eBeg = offsets[r0], eEnd = offsets[r1];
        int row = 0;  // relative row in [0, r1-r0)
        float4 qd = qrow[wid][0];
        int rowEnd = rend[wid][0];
        float di = qd.z;
        float acc = fmaxf(qd.x * w10 + qd.y * w11 + qd.z * bb, 0.0f);  // self
        if (eBeg + j < eEnd) chunkW[wid][0][j] = Q[csr16[eBeg + j]];
        int buf = 0;
        for (int base = eBeg; base < eEnd; base += 64) {
            int nbase = base + 64;
            bool hasNext = nbase < eEnd;   // wave-uniform
            float4 qn;
            if (hasNext && nbase + j < eEnd) qn = Q[csr16[nbase + j]];
            int cnt = min(64, eEnd - base);
            int k = 0;
            for (; k + 4 <= cnt; k += 4) {
                float4 q0 = chunkW[wid][buf][k + 0];
                float4 q1 = chunkW[wid][buf][k + 1];
                float4 q2 = chunkW[wid][buf][k + 2];
                float4 q3 = chunkW[wid][buf][k + 3];
                float t0 = fmaxf(q0.x * w10 + q0.y * w11 + q0.z * bb, 0.0f);
                float t1 = fmaxf(q1.x * w10 + q1.y * w11 + q1.z * bb, 0.0f);
                float t2 = fmaxf(q2.x * w10 + q2.y * w11 + q2.z * bb, 0.0f);
                float t3 = fmaxf(q3.x * w10 + q3.y * w11 + q3.z * bb, 0.0f);
                int e0 = base + k;
#pragma unroll
                for (int i = 0; i < 4; i++) {
                    while (e0 + i >= rowEnd) {   // row(s) complete (LDS only)
                        At[j][(r0 - rbase) + row] = di * acc;
                        row++;
                        rowEnd = rend[wid][row];
                        qd = qrow[wid][row];
                        di = qd.z;
                        acc = fmaxf(qd.x * w10 + qd.y * w11 + qd.z * bb, 0.0f);
                    }
                    acc += (i == 0) ? t0 : (i == 1) ? t1 : (i == 2) ? t2 : t3;
                }
            }
            for (; k < cnt; k++) {
                float4 q = chunkW[wid][buf][k];
                float tt = fmaxf(q.x * w10 + q.y * w11 + q.z * bb, 0.0f);
                int ecur = base + k;
                while (ecur >= rowEnd) {
                    At[j][(r0 - rbase) + row] = di * acc;
                    row++;
                    rowEnd = rend[wid][row];
                    qd = qrow[wid][row];
                    di = qd.z;
                    acc = fmaxf(qd.x * w10 + qd.y * w11 + qd.z * bb, 0.0f);
                }
                acc += tt;
            }
            if (hasNext) {
                if (nbase + j < eEnd) chunkW[wid][buf ^ 1][j] = qn;
                buf ^= 1;
            }
        }
        // flush remaining rows (incl. zero-degree tails)
        while (true) {
            At[j][(r0 - rbase) + row] = di * acc;
            row++;
            if (r0 + row >= r1) break;
            qd = qrow[wid][row];
            di = qd.z;
            acc = fmaxf(qd.x * w10 + qd.y * w11 + qd.z * bb, 0.0f);
        }
    }
    __syncthreads();
    // Phase 2: 4 rows x 2 cols per thread; col-major lanes -> coalesced stores.
    int rg = (tid >> 5) * 4;   // 0..60
    int cg = (tid & 31) * 2;   // 0..62
    float a2[4][2] = {{0.0f}};
#pragma unroll 8
    for (int k = 0; k < 64; k++) {
        float4 a = *reinterpret_cast<const float4*>(&At[k][rg]);
        float2 b = *reinterpret_cast<const float2*>(&Ws[k][cg]);
        a2[0][0] += a.x * b.x; a2[0][1] += a.x * b.y;
        a2[1][0] += a.y * b.x; a2[1][1] += a.y * b.y;
        a2[2][0] += a.z * b.x; a2[2][1] += a.z * b.y;
        a2[3][0] += a.w * b.x; a2[3][1] += a.w * b.y;
    }
#pragma unroll
    for (int i2 = 0; i2 < 4; i2++) {
        int r = rbase + rg + i2;
        if (r < N) {
            *reinterpret_cast<float2*>(&Bout[(size_t)r * H + cg]) = make_float2(
                fmaxf(a2[i2][0] + bs[cg + 0], 0.0f),
                fmaxf(a2[i2][1] + bs[cg + 1], 0.0f));
        }
    }
}

// Mean-pool per graph (sorted batch; inline binary search) + 64x3 classify.
// 4 partial accumulators pipeline the row loads.
__global__ __launch_bounds__(256) void k_poolcls(
    const float* __restrict__ B, const void* batch,
    const float* __restrict__ Wc, const float* __restrict__ bc,
    float* __restrict__ out, int N, int G, const int* __restrict__ flags) {
    int t = blockIdx.x * blockDim.x + threadIdx.x;
    int g = t >> 6, j = t & 63;
    if (g >= G) return;
    int is64 = flags[1];
    int beg, end;
    {
        int lo = 0, hi = N;
        while (lo < hi) {
            int mid = (lo + hi) >> 1;
            if (ld_idx(batch, mid, is64) < g) lo = mid + 1; else hi = mid;
        }
        beg = lo;
    }
    {
        int lo = beg, hi = N;
        while (lo < hi) {
            int mid = (lo + hi) >> 1;
            if (ld_idx(batch, mid, is64) < g + 1) lo = mid + 1; else hi = mid;
        }
        end = lo;
    }
    float a0 = 0, a1 = 0, a2 = 0, a3 = 0;
    int n = beg;
    for (; n + 4 <= end; n += 4) {
        a0 += B[(size_t)(n + 0) * H + j];
        a1 += B[(size_t)(n + 1) * H + j];
        a2 += B[(size_t)(n + 2) * H + j];
        a3 += B[(size_t)(n + 3) * H + j];
    }
    for (; n < end; n++) a0 += B[(size_t)n * H + j];
    float acc = (a0 + a1) + (a2 + a3);
    float p = acc / (float)max(end - beg, 1);
#pragma unroll
    for (int c = 0; c < 3; c++) {
        float v = p * Wc[j * 3 + c];
        for (int m = 32; m >= 1; m >>= 1) v += __shfl_xor(v, m);
        if (j == 0) out[g * 3 + c] = v + bc[c];
    }
}

extern "C" void kernel_launch(void* const* d_in, const int* in_sizes, int n_in,
                              void* d_out, int out_size, void* d_ws,
                              size_t ws_size, hipStream_t stream) {
    const float* x  = (const float*)d_in[0];
    const float* W1 = (const float*)d_in[1];
    const float* b1 = (const float*)d_in[2];
    const float* W2 = (const float*)d_in[3];
    const float* b2 = (const float*)d_in[4];
    const float* Wc = (const float*)d_in[5];
    const float* bc = (const float*)d_in[6];
    const void*  ei = d_in[7];
    const void*  batch = d_in[8];

    int N = in_sizes[0] / 2;
    int E = in_sizes[7] / 2;
    int G = out_size / 3;

    // Workspace layout (descending alignment).
    float4* Q       = (float4*)d_ws;                       // [N]
    float4* stats_part = Q + N;                            // [128]
    float*  B       = (float*)(stats_part + 128);          // [N,64]
    float2* T       = (float2*)(B + (size_t)N * H);        // [N]
    unsigned* packed = (unsigned*)(T + N);                 // [E]
    unsigned* binned = packed + E;                         // [E]
    unsigned short* csr16 = (unsigned short*)(binned + E); // [E]
    int*    histM   = (int*)(csr16 + ((E + 1) & ~1));      // [NB*NBLK]
    int*    counts  = histM + NB * NBLK;                   // [N]
    int*    offsets = counts + N;                          // [N+1]
    int*    bbase   = offsets + N + 1;                     // [NB+1]
    int*    bsum    = bbase + NB + 1;                      // [NB]
    float*  stats   = (float*)(bsum + NB);                 // [8]
    int*    flags   = (int*)(stats + 8);                   // [2]

    float* out = (float*)d_out;

    // 1) fused stats-partials + edge pack/histogram
    k_pre<<<384, 256, 0, stream>>>(x, N, stats_part, ei, E,
                                   (const int*)batch, in_sizes[8], flags,
                                   packed, histM);
    // 2) per-bucket scan (+ stats reduce in block 0)
    k_scanA<<<NB, NBLK, 0, stream>>>(histM, bsum, stats_part, stats);
    // 3) bucket bases (scanB folded in) + sentinels
    k_scanC<<<NB, NBLK, 0, stream>>>(histM, bsum, bbase, offsets, N, E);
    // 4) atomic-free partition
    k_part<<<NBLK, 256, 0, stream>>>(packed, histM, binned, E);
    // 5) per-bucket counting sort + prepT
    k_bsort<<<NB, NB, 0, stream>>>(binned, bbase, csr16, counts, offsets,
                                   x, stats, T, N);
    // 6) layer-1 rank-2 aggregation -> Q
    k_aggQ<<<(N * 4 + 255) / 256, 256, 0, stream>>>(csr16, offsets, T, counts,
                                                    Q, N);
    // 7) fused layer-2 aggregation + GEMM
    k_gathgemm<<<(N + 63) / 64, 512, 0, stream>>>(csr16, offsets, Q, W1, b1,
                                                  W2, b2, B, N);
    // 8) pool + classify
    k_poolcls<<<(G * H + 255) / 256, 256, 0, stream>>>(B, batch, Wc, bc, out,
                                                       N, G, flags);
}